// Round 7
// baseline (284.662 us; speedup 1.0000x reference)
//
#include <hip/hip_runtime.h>

// CrossModalAttentionScorer — round 7: round-5 fused (proven best) + retiled
// Qp (128x64, 4 blocks/CU) + retiled M2 (64x64, 256 blocks) + merged prep.
// B=16, R=1024, T=512, D=H=1024.
//
//   M2 = Wr @ Wq^T; Qp = NT(query, M2); cvec = q.(Wq br); bq cancels in softmax.
//   Fused: accS = NT(region,Qp)+cvec, accH = NT(Ws1+region*Ws2, query),
//   split-softmax stats per 64-col chunk; combine -> out.
//
// Round-6 lesson: 64x64 waves cost 236 unified regs -> 2 waves/SIMD; occupancy
// loss beat the 1.64x LDS-traffic gain. Round-5 shape (32x64, 128 regs,
// 4 waves/SIMD) is the fused winner. This round attacks Qp/M2 latency instead.

#define BD 16
#define RD 1024
#define TD 512
#define DD 1024
#define BR (BD * RD)

typedef _Float16 half8 __attribute__((ext_vector_type(8)));
typedef _Float16 half4 __attribute__((ext_vector_type(4)));
typedef float floatx4 __attribute__((ext_vector_type(4)));

__device__ __forceinline__ float wave_sum(float v) {
#pragma unroll
  for (int off = 32; off > 0; off >>= 1) v += __shfl_down(v, off);
  return v;
}

// ---------------- simple NT GEMM, 256 thr = 4 waves (2x2), wave BM/2 x BN/2.
// Pipelined: reg-prefetch 2 iters ahead, LDS double-buffer, 1 barrier/iter.
// remap==1: Qp mapping (1024 blocks, XCD m-strips). else natural 2-D grid.
template <int BM, int BN>
__global__ __launch_bounds__(256, 4) void gemm_s(
    const _Float16* __restrict__ A, const _Float16* __restrict__ B,
    _Float16* __restrict__ C, int N, int K, int remap) {
  constexpr int MI = BM / 32;  // fragment count per wave (WM=BM/2)
  constexpr int NJ = BN / 32;
  constexpr int ASZ = BM * 32, BSZ = BN * 32;
  constexpr int AP = BM / 64;  // A staging passes
  __shared__ __align__(16) _Float16 lds[2 * (ASZ + BSZ)];

  int mt, nt;
  if (remap == 1) {  // 1024 blocks: XCD s owns m-strip [8s, 8s+8)
    const int lin = blockIdx.x;
    const int s = lin & 7, u = lin >> 3;
    mt = s * 8 + (u >> 4);
    nt = u & 15;
  } else {
    mt = blockIdx.y;
    nt = blockIdx.x;
  }
  const int m0 = mt * BM, n0 = nt * BN;
  const int tid = threadIdx.x, lane = tid & 63, w = tid >> 6;
  const int wr = w >> 1, wc = w & 1;

  // Staging: 256 threads cover 64 rows x 4 chunks/pass; xor-swizzled chunks
  // (r3-proven: 0 bank conflicts; swizzle idx (row>>1)&3 invariant under +64).
  const int srow = tid >> 2, slot = tid & 3;
  const int scol = (slot ^ ((srow >> 1) & 3)) * 8;
  const int wofs = srow * 32 + slot * 8;
  const long offA = (long)(m0 + srow) * K + scol;
  const long offB = (long)(n0 + srow) * K + scol;
  const long rstep = (long)64 * K;

  const int NK = K / 32;
  int4 pA[AP], pB[1];
#pragma unroll
  for (int p = 0; p < AP; ++p) pA[p] = *(const int4*)(A + offA + p * rstep);
  pB[0] = *(const int4*)(B + offB);
#pragma unroll
  for (int p = 0; p < AP; ++p) *(int4*)&lds[wofs + p * 2048] = pA[p];
  *(int4*)&lds[ASZ + wofs] = pB[0];
  if (NK > 1) {
#pragma unroll
    for (int p = 0; p < AP; ++p) pA[p] = *(const int4*)(A + offA + p * rstep + 32);
    pB[0] = *(const int4*)(B + offB + 32);
  }
  __syncthreads();

  floatx4 acc[MI][NJ] = {};
  const int fr = lane & 15, g = lane >> 4;
  const int fs = (g ^ ((fr >> 1) & 3)) * 8;

  for (int kt = 0; kt < NK; ++kt) {
    const int cur = (kt & 1) * (ASZ + BSZ);
    const int nxt = ((kt + 1) & 1) * (ASZ + BSZ);
    if (kt + 1 < NK) {
#pragma unroll
      for (int p = 0; p < AP; ++p) *(int4*)&lds[nxt + wofs + p * 2048] = pA[p];
      *(int4*)&lds[nxt + ASZ + wofs] = pB[0];
    }
    if (kt + 2 < NK) {
      const long go = (long)(kt + 2) * 32;
#pragma unroll
      for (int p = 0; p < AP; ++p) pA[p] = *(const int4*)(A + offA + p * rstep + go);
      pB[0] = *(const int4*)(B + offB + go);
    }
    half8 af[MI], bf[NJ];
#pragma unroll
    for (int i = 0; i < MI; ++i)
      af[i] = *(const half8*)&lds[cur + ((BM / 2) * wr + 16 * i + fr) * 32 + fs];
#pragma unroll
    for (int j = 0; j < NJ; ++j)
      bf[j] = *(const half8*)&lds[cur + ASZ + ((BN / 2) * wc + 16 * j + fr) * 32 + fs];
#pragma unroll
    for (int i = 0; i < MI; ++i)
#pragma unroll
      for (int j = 0; j < NJ; ++j)
        acc[i][j] = __builtin_amdgcn_mfma_f32_16x16x32_f16(af[i], bf[j], acc[i][j], 0, 0, 0);
    __syncthreads();
  }

  // C/D layout: col = lane&15, row = g*4 + reg.
  const int cr = g * 4, cc = fr;
#pragma unroll
  for (int i = 0; i < MI; ++i)
#pragma unroll
    for (int r = 0; r < 4; ++r)
#pragma unroll
      for (int j = 0; j < NJ; ++j)
        C[(long)(m0 + (BM / 2) * wr + 16 * i + cr + r) * N + n0 + (BN / 2) * wc +
          16 * j + cc] = (_Float16)acc[i][j][r];
}

// ---------------- fused S/H GEMM — round-5 exact config (proven 46.7 us).
// 512 thr = 8 waves (4x2), wave 32x64, acc 64+64 regs -> 4 waves/SIMD.
__global__ __launch_bounds__(512, 4) void gemm_fused(
    const _Float16* __restrict__ A, const _Float16* __restrict__ B0,
    const _Float16* __restrict__ B1,
    float* __restrict__ Ms, float* __restrict__ Ls, float* __restrict__ Hs,
    const float* __restrict__ cvec, const _Float16* __restrict__ wsh,
    int K, long sA, long sB) {
  __shared__ __align__(16) _Float16 lds[2 * 3 * 4096];
  __shared__ __align__(16) _Float16 wlds[2048];

  const int lin = blockIdx.x;
  const int s = lin & 7, u = lin >> 3;   // XCD s owns batches 2s, 2s+1
  const int b = 2 * s + (u >> 5);
  const int t = u & 31;
  const int mt = t >> 2, nt = t & 3;
  const int m0 = mt * 128, n0 = nt * 128;
  A += (long)b * sA;
  B0 += (long)b * sB;
  B1 += (long)b * sB;

  const int tid = threadIdx.x, lane = tid & 63, w = tid >> 6;
  const int wr = w >> 1, wc = w & 1;

  const int lrow = lane >> 2;
  const int slot = lane & 3;
  const int scol = (slot ^ ((lrow >> 1) & 3)) * 8;
  const int srow = 16 * w + lrow;  // 0..127
  const _Float16* gA = A + (long)(m0 + srow) * K + scol;
  const _Float16* gP = B0 + (long)(n0 + srow) * K + scol;
  const _Float16* gQ = B1 + (long)(n0 + srow) * K + scol;
  const int wofs = srow * 32 + slot * 8;

  if (tid < 256) *(int4*)&wlds[tid * 8] = *(const int4*)&wsh[tid * 8];

  const int NK = K / 32;
  int4 pA, pP, pQ;
  pA = *(const int4*)gA;
  pP = *(const int4*)gP;
  pQ = *(const int4*)gQ;
  *(int4*)&lds[wofs] = pA;
  *(int4*)&lds[4096 + wofs] = pP;
  *(int4*)&lds[8192 + wofs] = pQ;
  if (NK > 1) {
    pA = *(const int4*)(gA + 32);
    pP = *(const int4*)(gP + 32);
    pQ = *(const int4*)(gQ + 32);
  }
  __syncthreads();

  floatx4 accS[2][4] = {};
  floatx4 accH[2][4] = {};
  const int fr = lane & 15, g = lane >> 4;
  const int fs = (g ^ ((fr >> 1) & 3)) * 8;

  for (int kt = 0; kt < NK; ++kt) {
    const int cur = (kt & 1) * 12288;
    const int nxt = ((kt + 1) & 1) * 12288;
    if (kt + 1 < NK) {
      *(int4*)&lds[nxt + wofs] = pA;
      *(int4*)&lds[nxt + 4096 + wofs] = pP;
      *(int4*)&lds[nxt + 8192 + wofs] = pQ;
    }
    if (kt + 2 < NK) {
      const long go = (long)(kt + 2) * 32;
      pA = *(const int4*)(gA + go);
      pP = *(const int4*)(gP + go);
      pQ = *(const int4*)(gQ + go);
    }
    half8 af[2], bp[4], bq[4], w1f, w2f;
#pragma unroll
    for (int i = 0; i < 2; ++i)
      af[i] = *(const half8*)&lds[cur + (32 * wr + 16 * i + fr) * 32 + fs];
#pragma unroll
    for (int j = 0; j < 4; ++j)
      bp[j] = *(const half8*)&lds[cur + 4096 + (64 * wc + 16 * j + fr) * 32 + fs];
#pragma unroll
    for (int j = 0; j < 4; ++j)
      bq[j] = *(const half8*)&lds[cur + 8192 + (64 * wc + 16 * j + fr) * 32 + fs];
    w1f = *(const half8*)&wlds[kt * 32 + g * 8];
    w2f = *(const half8*)&wlds[1024 + kt * 32 + g * 8];
#pragma unroll
    for (int i = 0; i < 2; ++i)
#pragma unroll
      for (int j = 0; j < 4; ++j)
        accS[i][j] = __builtin_amdgcn_mfma_f32_16x16x32_f16(af[i], bp[j], accS[i][j], 0, 0, 0);
#pragma unroll
    for (int i = 0; i < 2; ++i) af[i] = w1f + af[i] * w2f;  // A' for H
#pragma unroll
    for (int i = 0; i < 2; ++i)
#pragma unroll
      for (int j = 0; j < 4; ++j)
        accH[i][j] = __builtin_amdgcn_mfma_f32_16x16x32_f16(af[i], bq[j], accH[i][j], 0, 0, 0);
    __syncthreads();
  }

  // C/D layout: col = lane&15, row = g*4 + reg.
  const int cr = g * 4, cc = fr;
  float cv[4];
#pragma unroll
  for (int j = 0; j < 4; ++j)
    cv[j] = cvec[(long)b * TD + n0 + 64 * wc + 16 * j + cc];
  const int chunk = nt * 2 + wc;  // 64-col chunk 0..7
  const long rowBase = (long)b * RD + m0 + 32 * wr + cr;
#pragma unroll
  for (int i = 0; i < 2; ++i) {
#pragma unroll
    for (int r = 0; r < 4; ++r) {
      float mx = -1e30f;
#pragma unroll
      for (int j = 0; j < 4; ++j) mx = fmaxf(mx, accS[i][j][r] + cv[j]);
      mx = fmaxf(mx, __shfl_xor(mx, 1));
      mx = fmaxf(mx, __shfl_xor(mx, 2));
      mx = fmaxf(mx, __shfl_xor(mx, 4));
      mx = fmaxf(mx, __shfl_xor(mx, 8));
      float l = 0.f, hs = 0.f;
#pragma unroll
      for (int j = 0; j < 4; ++j) {
        const float e = __expf(accS[i][j][r] + cv[j] - mx);
        l += e;
        hs += e * accH[i][j][r];
      }
      l += __shfl_xor(l, 1); hs += __shfl_xor(hs, 1);
      l += __shfl_xor(l, 2); hs += __shfl_xor(hs, 2);
      l += __shfl_xor(l, 4); hs += __shfl_xor(hs, 4);
      l += __shfl_xor(l, 8); hs += __shfl_xor(hs, 8);
      if (cc == 0) {
        const long idx = (long)chunk * BR + rowBase + 16 * i + r;
        Ms[idx] = mx;
        Ls[idx] = l;
        Hs[idx] = hs;
      }
    }
  }
}

// Combine 8 chunk-stats per row: out = HS/L + rdvec + bs.
__global__ __launch_bounds__(256) void combine(
    const float* __restrict__ Ms, const float* __restrict__ Ls,
    const float* __restrict__ Hs, const float* __restrict__ rdvec,
    const float* __restrict__ bs, float* __restrict__ out) {
  const int row = blockIdx.x * 256 + threadIdx.x;
  float mv[8];
  float gm = -1e30f;
#pragma unroll
  for (int c = 0; c < 8; ++c) {
    mv[c] = Ms[(long)c * BR + row];
    gm = fmaxf(gm, mv[c]);
  }
  float L = 0.f, HS = 0.f;
#pragma unroll
  for (int c = 0; c < 8; ++c) {
    const float s = __expf(mv[c] - gm);
    L += Ls[(long)c * BR + row] * s;
    HS += Hs[(long)c * BR + row] * s;
  }
  out[row] = HS / L + rdvec[row] + bs[0];
}

// prep + conv_region merged (independent work):
//   blk [0,1024)        Wr->fp16
//   blk [1024,2048)     Wq->fp16
//   blk [2048,2050)     Ws1|Ws2 -> fp16
//   blk [2050,2306)     wqbr = Wq @ br
//   blk [2306,2306+16K) conv_region row blk-2306: region->fp16 + rdvec
__global__ __launch_bounds__(256) void prep_region(
    const float* __restrict__ Wr, const float* __restrict__ Wq,
    const float* __restrict__ Ws, const float* __restrict__ br,
    const float* __restrict__ region,
    _Float16* __restrict__ Wr16, _Float16* __restrict__ Wq16,
    _Float16* __restrict__ Ws16, float* __restrict__ wqbr,
    _Float16* __restrict__ r16, float* __restrict__ rdvec) {
  const int blk = blockIdx.x, tid = threadIdx.x;
  if (blk < 2050) {
    const float* src;
    _Float16* dst;
    long i;
    if (blk < 1024) { src = Wr; dst = Wr16; i = (long)blk * 1024 + tid * 4; }
    else if (blk < 2048) { src = Wq; dst = Wq16; i = (long)(blk - 1024) * 1024 + tid * 4; }
    else { src = Ws + DD; dst = Ws16; i = (long)(blk - 2048) * 1024 + tid * 4; }
    const float4 v = *(const float4*)&src[i];
    half4 h = {(_Float16)v.x, (_Float16)v.y, (_Float16)v.z, (_Float16)v.w};
    *(half4*)&dst[i] = h;
  } else if (blk < 2306) {
    const int row = (blk - 2050) * 4 + (tid >> 6);
    const int lane = tid & 63;
    const float* x = Wq + (long)row * DD;
    float s = 0.f;
    for (int k = lane; k < DD; k += 64) s += x[k] * br[k];
    s = wave_sum(s);
    if (lane == 0) wqbr[row] = s;
  } else {
    const long row = blk - 2306;
    const int lane = tid & 63, wid = tid >> 6;
    const long i = row * DD + tid * 4;
    const float4 v = *(const float4*)&region[i];
    half4 h = {(_Float16)v.x, (_Float16)v.y, (_Float16)v.z, (_Float16)v.w};
    *(half4*)&r16[i] = h;
    const float4 w0 = *(const float4*)&Ws[tid * 4];
    float rd = v.x * w0.x + v.y * w0.y + v.z * w0.z + v.w * w0.w;
    rd = wave_sum(rd);
    __shared__ float sm[4];
    if (lane == 0) sm[wid] = rd;
    __syncthreads();
    if (tid == 0) rdvec[row] = sm[0] + sm[1] + sm[2] + sm[3];
  }
}

// One block per (b,t) row: query -> fp16, cvec[row] = q.(Wq br). After prep.
__global__ __launch_bounds__(256) void conv_query(
    const float* __restrict__ query, const float* __restrict__ wqbr,
    _Float16* __restrict__ q16, float* __restrict__ cvec) {
  const long row = blockIdx.x;
  const int tid = threadIdx.x, lane = tid & 63, wid = tid >> 6;
  const long i = row * DD + tid * 4;
  const float4 v = *(const float4*)&query[i];
  half4 h = {(_Float16)v.x, (_Float16)v.y, (_Float16)v.z, (_Float16)v.w};
  *(half4*)&q16[i] = h;
  const float4 w = *(const float4*)&wqbr[tid * 4];
  float c = v.x * w.x + v.y * w.y + v.z * w.z + v.w * w.w;
  c = wave_sum(c);
  __shared__ float sm[4];
  if (lane == 0) sm[wid] = c;
  __syncthreads();
  if (tid == 0) cvec[row] = sm[0] + sm[1] + sm[2] + sm[3];
}

extern "C" void kernel_launch(void* const* d_in, const int* in_sizes, int n_in,
                              void* d_out, int out_size, void* d_ws, size_t ws_size,
                              hipStream_t stream) {
  const float* region = (const float*)d_in[0];
  const float* query  = (const float*)d_in[1];
  const float* Wr     = (const float*)d_in[2];
  const float* br     = (const float*)d_in[3];
  const float* Wq     = (const float*)d_in[4];
  // d_in[5] = bq: t-constant per score row, cancels in softmax.
  const float* Ws     = (const float*)d_in[6];
  const float* bs     = (const float*)d_in[7];
  float* out = (float*)d_out;

  // ws layout (~74 MiB).
  char* p = (char*)d_ws;
  _Float16* region16 = (_Float16*)p;                   // 32 MiB
  _Float16* query16  = (_Float16*)(p + (32u << 20));   // 16 MiB
  _Float16* Qp       = (_Float16*)(p + (48u << 20));   // 16 MiB
  _Float16* Wr16     = (_Float16*)(p + (64u << 20));   // 2 MiB
  _Float16* Wq16     = (_Float16*)(p + (66u << 20));   // 2 MiB
  _Float16* M2       = (_Float16*)(p + (68u << 20));   // 2 MiB
  _Float16* Ws16     = (_Float16*)(p + (70u << 20));   // 4 KiB (Ws1|Ws2)
  float*    wqbr     = (float*)(p + (70u << 20) + 65536);
  float*    cvec     = wqbr + 1024;
  float*    rdvec    = cvec + BD * TD;
  float*    Ms       = (float*)(p + (72u << 20));      // 3 x 512 KiB stats
  float*    Ls       = Ms + 8 * BR;
  float*    Hs       = Ls + 8 * BR;

  // Weights + region conversions (independent), then query (needs wqbr).
  prep_region<<<dim3(2306 + BD * RD), 256, 0, stream>>>(
      Wr, Wq, Ws, br, region, Wr16, Wq16, Ws16, wqbr, region16, rdvec);
  conv_query<<<dim3(BD * TD), 256, 0, stream>>>(query, wqbr, query16, cvec);

  // M2 = Wr @ Wq^T  [D,D] fp16 — 64x64 tiles, 256 blocks (1/CU).
  gemm_s<64, 64><<<dim3(16, 16), 256, 0, stream>>>(Wr16, Wq16, M2, DD, DD, 0);
  // Qp = query @ M2^T  [B*T, D] fp16 — 128x64 tiles, 1024 blocks (4/CU),
  // XCD m-strips (2 MB A-strip + 2 MB M2 per XCD L2).
  gemm_s<128, 64><<<dim3(1024), 256, 0, stream>>>(query16, M2, Qp, DD, DD, 1);
  // Fused S/H + split-softmax stats (round-5 config), XCD batch-pairs.
  gemm_fused<<<dim3(512), 512, 0, stream>>>(
      region16, Qp, query16, Ms, Ls, Hs, cvec, Ws16,
      DD, (long)RD * DD, (long)TD * DD);
  // out = HS/L + region.Ws0 + bs.
  combine<<<dim3(BR / 256), 256, 0, stream>>>(Ms, Ls, Hs, rdvec, bs, out);
}

// Round 8
// 225.531 us; speedup vs baseline: 1.2622x; 1.2622x over previous
//
#include <hip/hip_runtime.h>

// CrossModalAttentionScorer — round 8: 4 launches (was 7).
// B=16, R=1024, T=512, D=H=1024.
//
//   K1 prep_all: M2 = NT(Wr,Wq) w/ inline fp32->fp16 staging; Ws16; wqbr(+16);
//                region16 + rdvec(=region.Ws0); query16.
//   K2 qp:       Qp = NT(query16, M2), r5-proven 512thr/128x128 shape, with
//                cvec[t] = q.(Wq br) accumulated from staged regs (free).
//   K3 fused:    accS = NT(region,Qp)+cvec, accH = NT(Ws1+region*Ws2, query);
//                wave layout 2x4 (64x32/wave): 8 LDS reads per 16 MFMA (r5: 10)
//                at the same 128 acc regs (r6's mistake: paid regs for this).
//   K4 combine:  out = HS/L + rdvec + bs over 16 col-chunks.
//
// r7 lesson: smaller tiles for more blocks (128x64) cratered (87us, MfmaUtil
// 7.5%, 3x write amplification). ~10us/launch overhead => cut launches.

#define BD 16
#define RD 1024
#define TD 512
#define DD 1024
#define BR (BD * RD)

typedef _Float16 half8 __attribute__((ext_vector_type(8)));
typedef _Float16 half4 __attribute__((ext_vector_type(4)));
typedef float floatx4 __attribute__((ext_vector_type(4)));

__device__ __forceinline__ float wave_sum(float v) {
#pragma unroll
  for (int off = 32; off > 0; off >>= 1) v += __shfl_down(v, off);
  return v;
}

__device__ __forceinline__ half8 cvt8(float4 a, float4 b) {
  half8 h = {(_Float16)a.x, (_Float16)a.y, (_Float16)a.z, (_Float16)a.w,
             (_Float16)b.x, (_Float16)b.y, (_Float16)b.z, (_Float16)b.w};
  return h;
}

// ---------------- K1: everything independent, one launch. 256 threads.
// blk [0,256):            M2 GEMM 64x64 tile (fp32 staged, converted inline)
// blk [256,258):          Ws1|Ws2 -> fp16
// blk [258,514):          wqbr = Wq @ br (fp32 + fp16 copies)
// blk [514,514+16384):    region -> fp16, rdvec = region.Ws0
// blk [16898,16898+8192): query -> fp16
__global__ __launch_bounds__(256) void prep_all(
    const float* __restrict__ Wr, const float* __restrict__ Wq,
    const float* __restrict__ Ws, const float* __restrict__ br,
    const float* __restrict__ region, const float* __restrict__ query,
    _Float16* __restrict__ M2, _Float16* __restrict__ Ws16,
    float* __restrict__ wqbr, _Float16* __restrict__ wqbr16,
    _Float16* __restrict__ r16, float* __restrict__ rdvec,
    _Float16* __restrict__ q16) {
  __shared__ __align__(16) _Float16 lds[2 * 2 * 2048];  // 16 KB (M2 path)
  __shared__ float sm[4];
  const int blk = blockIdx.x, tid = threadIdx.x;

  if (blk < 256) {  // ---- M2 = NT(Wr, Wq), 64x64 tile, K=1024
    const int m0 = (blk >> 4) * 64, n0 = (blk & 15) * 64;
    const int lane = tid & 63, w = tid >> 6;
    const int wr = w >> 1, wc = w & 1;
    const int srow = tid >> 2, slot = tid & 3;
    const int scol = (slot ^ ((srow >> 1) & 3)) * 8;
    const long offA = (long)(m0 + srow) * DD + scol;
    const long offB = (long)(n0 + srow) * DD + scol;
    const int wofs = srow * 32 + slot * 8;
    const int NK = DD / 32;
    float4 a0, a1, b0, b1;
    a0 = *(const float4*)(Wr + offA); a1 = *(const float4*)(Wr + offA + 4);
    b0 = *(const float4*)(Wq + offB); b1 = *(const float4*)(Wq + offB + 4);
    *(int4*)&lds[wofs] = *(int4*)&(const half8&)cvt8(a0, a1);
    {
      half8 hb = cvt8(b0, b1);
      *(half8*)&lds[2048 + wofs] = hb;
    }
    a0 = *(const float4*)(Wr + offA + 32); a1 = *(const float4*)(Wr + offA + 36);
    b0 = *(const float4*)(Wq + offB + 32); b1 = *(const float4*)(Wq + offB + 36);
    __syncthreads();
    floatx4 acc[2][2] = {};
    const int fr = lane & 15, g = lane >> 4;
    const int fs = (g ^ ((fr >> 1) & 3)) * 8;
    for (int kt = 0; kt < NK; ++kt) {
      const int cur = (kt & 1) * 4096, nxt = ((kt + 1) & 1) * 4096;
      if (kt + 1 < NK) {
        half8 ha = cvt8(a0, a1), hb = cvt8(b0, b1);
        *(half8*)&lds[nxt + wofs] = ha;
        *(half8*)&lds[nxt + 2048 + wofs] = hb;
      }
      if (kt + 2 < NK) {
        const long go = (long)(kt + 2) * 32;
        a0 = *(const float4*)(Wr + offA + go); a1 = *(const float4*)(Wr + offA + go + 4);
        b0 = *(const float4*)(Wq + offB + go); b1 = *(const float4*)(Wq + offB + go + 4);
      }
      half8 af[2], bf[2];
#pragma unroll
      for (int i = 0; i < 2; ++i)
        af[i] = *(const half8*)&lds[cur + (32 * wr + 16 * i + fr) * 32 + fs];
#pragma unroll
      for (int j = 0; j < 2; ++j)
        bf[j] = *(const half8*)&lds[cur + 2048 + (32 * wc + 16 * j + fr) * 32 + fs];
#pragma unroll
      for (int i = 0; i < 2; ++i)
#pragma unroll
        for (int j = 0; j < 2; ++j)
          acc[i][j] = __builtin_amdgcn_mfma_f32_16x16x32_f16(af[i], bf[j], acc[i][j], 0, 0, 0);
      __syncthreads();
    }
    const int cr = g * 4, cc = fr;
#pragma unroll
    for (int i = 0; i < 2; ++i)
#pragma unroll
      for (int r = 0; r < 4; ++r)
#pragma unroll
        for (int j = 0; j < 2; ++j)
          M2[(long)(m0 + 32 * wr + 16 * i + cr + r) * DD + n0 + 32 * wc + 16 * j + cc] =
              (_Float16)acc[i][j][r];
  } else if (blk < 258) {  // ---- Ws1|Ws2
    const long i = (long)(blk - 256) * 1024 + tid * 4;
    const float4 v = *(const float4*)&Ws[DD + i];
    half4 h = {(_Float16)v.x, (_Float16)v.y, (_Float16)v.z, (_Float16)v.w};
    *(half4*)&Ws16[i] = h;
  } else if (blk < 514) {  // ---- wqbr = Wq @ br
    const int row = (blk - 258) * 4 + (tid >> 6);
    const int lane = tid & 63;
    const float* x = Wq + (long)row * DD;
    float s = 0.f;
    for (int k = lane; k < DD; k += 64) s += x[k] * br[k];
    s = wave_sum(s);
    if (lane == 0) {
      wqbr[row] = s;
      wqbr16[row] = (_Float16)s;
    }
  } else if (blk < 514 + BR) {  // ---- region conv + rdvec
    const long row = blk - 514;
    const int lane = tid & 63, wid = tid >> 6;
    const long i = row * DD + tid * 4;
    const float4 v = *(const float4*)&region[i];
    half4 h = {(_Float16)v.x, (_Float16)v.y, (_Float16)v.z, (_Float16)v.w};
    *(half4*)&r16[i] = h;
    const float4 w0 = *(const float4*)&Ws[tid * 4];
    float rd = v.x * w0.x + v.y * w0.y + v.z * w0.z + v.w * w0.w;
    rd = wave_sum(rd);
    if (lane == 0) sm[wid] = rd;
    __syncthreads();
    if (tid == 0) rdvec[row] = sm[0] + sm[1] + sm[2] + sm[3];
  } else {  // ---- query conv
    const long row = blk - (514 + BR);
    const long i = row * DD + tid * 4;
    const float4 v = *(const float4*)&query[i];
    half4 h = {(_Float16)v.x, (_Float16)v.y, (_Float16)v.z, (_Float16)v.w};
    *(half4*)&q16[i] = h;
  }
}

// ---------------- K2: Qp = NT(query16, M2) — r5-proven 512thr/128x128 shape,
// wave 32x64, XCD m-strips; cvec accumulated from staged A regs.
__global__ __launch_bounds__(512, 4) void qp_gemm(
    const _Float16* __restrict__ A, const _Float16* __restrict__ B,
    _Float16* __restrict__ C, const _Float16* __restrict__ wq16,
    float* __restrict__ cvec) {
  __shared__ __align__(16) _Float16 lds[2 * 2 * 4096];  // 32 KB
  const int lin = blockIdx.x;
  const int s = lin & 7, u = lin >> 3;  // XCD s owns m-strip [8s, 8s+8)
  const int mt = s * 8 + (u >> 3), nt = u & 7;
  const int m0 = mt * 128, n0 = nt * 128;
  const int tid = threadIdx.x, lane = tid & 63, w = tid >> 6;
  const int wr = w >> 1, wc = w & 1;

  const int lrow = lane >> 2, slot = lane & 3;
  const int scol = (slot ^ ((lrow >> 1) & 3)) * 8;
  const int srow = 16 * w + lrow;  // 0..127
  const _Float16* gA = A + (long)(m0 + srow) * DD + scol;
  const _Float16* gB = B + (long)(n0 + srow) * DD + scol;
  const int wofs = srow * 32 + slot * 8;

  const int NK = DD / 32;
  float cvp = 0.f;
  int4 pA, pB;
  pA = *(const int4*)gA;
  pB = *(const int4*)gB;
  {  // tile-0 cvec contribution (q chunk is in pA)
    half8 qa, wb;
    __builtin_memcpy(&qa, &pA, 16);
    wb = *(const half8*)&wq16[scol];
#pragma unroll
    for (int e = 0; e < 8; ++e) cvp += (float)qa[e] * (float)wb[e];
  }
  *(int4*)&lds[wofs] = pA;
  *(int4*)&lds[4096 + wofs] = pB;
  pA = *(const int4*)(gA + 32);
  pB = *(const int4*)(gB + 32);
  __syncthreads();

  floatx4 acc[2][4] = {};
  const int fr = lane & 15, g = lane >> 4;
  const int fs = (g ^ ((fr >> 1) & 3)) * 8;

  for (int kt = 0; kt < NK; ++kt) {
    const int cur = (kt & 1) * 8192, nxt = ((kt + 1) & 1) * 8192;
    if (kt + 1 < NK) {
      half8 qa, wb;
      __builtin_memcpy(&qa, &pA, 16);
      wb = *(const half8*)&wq16[(kt + 1) * 32 + scol];
#pragma unroll
      for (int e = 0; e < 8; ++e) cvp += (float)qa[e] * (float)wb[e];
      *(int4*)&lds[nxt + wofs] = pA;
      *(int4*)&lds[nxt + 4096 + wofs] = pB;
    }
    if (kt + 2 < NK) {
      const long go = (long)(kt + 2) * 32;
      pA = *(const int4*)(gA + go);
      pB = *(const int4*)(gB + go);
    }
    half8 af[2], bf[4];
#pragma unroll
    for (int i = 0; i < 2; ++i)
      af[i] = *(const half8*)&lds[cur + (32 * wr + 16 * i + fr) * 32 + fs];
#pragma unroll
    for (int j = 0; j < 4; ++j)
      bf[j] = *(const half8*)&lds[cur + 4096 + (64 * wc + 16 * j + fr) * 32 + fs];
#pragma unroll
    for (int i = 0; i < 2; ++i)
#pragma unroll
      for (int j = 0; j < 4; ++j)
        acc[i][j] = __builtin_amdgcn_mfma_f32_16x16x32_f16(af[i], bf[j], acc[i][j], 0, 0, 0);
    __syncthreads();
  }

  // cvec: 4 staging threads per A row (slots 0..3 = adjacent lanes).
  cvp += __shfl_xor(cvp, 1);
  cvp += __shfl_xor(cvp, 2);
  if (nt == 0 && slot == 0) cvec[m0 + srow] = cvp;

  const int cr = g * 4, cc = fr;
#pragma unroll
  for (int i = 0; i < 2; ++i)
#pragma unroll
    for (int r = 0; r < 4; ++r)
#pragma unroll
      for (int j = 0; j < 4; ++j)
        C[(long)(m0 + 32 * wr + 16 * i + cr + r) * DD + n0 + 64 * wc + 16 * j + cc] =
            (_Float16)acc[i][j][r];
}

// ---------------- K3: fused S/H GEMM + split-softmax stats.
// 512 thr = 8 waves in 2(m) x 4(n); wave 64x32: af[4]+bp[2]+bq[2] = 8 LDS
// reads / 16 MFMA (r5: 10), acc 128 regs (same as r5). XCD batch-pairs.
__global__ __launch_bounds__(512, 4) void gemm_fused(
    const _Float16* __restrict__ A, const _Float16* __restrict__ B0,
    const _Float16* __restrict__ B1,
    float* __restrict__ Ms, float* __restrict__ Ls, float* __restrict__ Hs,
    const float* __restrict__ cvec, const _Float16* __restrict__ wsh,
    long sA, long sB) {
  __shared__ __align__(16) _Float16 lds[2 * 3 * 4096];
  __shared__ __align__(16) _Float16 wlds[2048];

  const int lin = blockIdx.x;
  const int s = lin & 7, u = lin >> 3;  // XCD s owns batches 2s, 2s+1
  const int b = 2 * s + (u >> 5);
  const int t = u & 31;
  const int mt = t >> 2, nt = t & 3;
  const int m0 = mt * 128, n0 = nt * 128;
  A += (long)b * sA;
  B0 += (long)b * sB;
  B1 += (long)b * sB;

  const int tid = threadIdx.x, lane = tid & 63, w = tid >> 6;
  const int wr = w >> 2, wc = w & 3;  // 2 x 4

  const int lrow = lane >> 2, slot = lane & 3;
  const int scol = (slot ^ ((lrow >> 1) & 3)) * 8;
  const int srow = 16 * w + lrow;  // 0..127
  const _Float16* gA = A + (long)(m0 + srow) * DD + scol;
  const _Float16* gP = B0 + (long)(n0 + srow) * DD + scol;
  const _Float16* gQ = B1 + (long)(n0 + srow) * DD + scol;
  const int wofs = srow * 32 + slot * 8;

  if (tid < 256) *(int4*)&wlds[tid * 8] = *(const int4*)&wsh[tid * 8];

  const int NK = DD / 32;
  int4 pA, pP, pQ;
  pA = *(const int4*)gA;
  pP = *(const int4*)gP;
  pQ = *(const int4*)gQ;
  *(int4*)&lds[wofs] = pA;
  *(int4*)&lds[4096 + wofs] = pP;
  *(int4*)&lds[8192 + wofs] = pQ;
  pA = *(const int4*)(gA + 32);
  pP = *(const int4*)(gP + 32);
  pQ = *(const int4*)(gQ + 32);
  __syncthreads();

  floatx4 accS[4][2] = {};
  floatx4 accH[4][2] = {};
  const int fr = lane & 15, g = lane >> 4;
  const int fs = (g ^ ((fr >> 1) & 3)) * 8;

  for (int kt = 0; kt < NK; ++kt) {
    const int cur = (kt & 1) * 12288;
    const int nxt = ((kt + 1) & 1) * 12288;
    if (kt + 1 < NK) {
      *(int4*)&lds[nxt + wofs] = pA;
      *(int4*)&lds[nxt + 4096 + wofs] = pP;
      *(int4*)&lds[nxt + 8192 + wofs] = pQ;
    }
    if (kt + 2 < NK) {
      const long go = (long)(kt + 2) * 32;
      pA = *(const int4*)(gA + go);
      pP = *(const int4*)(gP + go);
      pQ = *(const int4*)(gQ + go);
    }
    half8 af[4], bp[2], bq[2], w1f, w2f;
#pragma unroll
    for (int i = 0; i < 4; ++i)
      af[i] = *(const half8*)&lds[cur + (64 * wr + 16 * i + fr) * 32 + fs];
#pragma unroll
    for (int j = 0; j < 2; ++j)
      bp[j] = *(const half8*)&lds[cur + 4096 + (32 * wc + 16 * j + fr) * 32 + fs];
#pragma unroll
    for (int j = 0; j < 2; ++j)
      bq[j] = *(const half8*)&lds[cur + 8192 + (32 * wc + 16 * j + fr) * 32 + fs];
    w1f = *(const half8*)&wlds[kt * 32 + g * 8];
    w2f = *(const half8*)&wlds[1024 + kt * 32 + g * 8];
#pragma unroll
    for (int i = 0; i < 4; ++i)
#pragma unroll
      for (int j = 0; j < 2; ++j)
        accS[i][j] = __builtin_amdgcn_mfma_f32_16x16x32_f16(af[i], bp[j], accS[i][j], 0, 0, 0);
#pragma unroll
    for (int i = 0; i < 4; ++i) af[i] = w1f + af[i] * w2f;  // A' for H
#pragma unroll
    for (int i = 0; i < 4; ++i)
#pragma unroll
      for (int j = 0; j < 2; ++j)
        accH[i][j] = __builtin_amdgcn_mfma_f32_16x16x32_f16(af[i], bq[j], accH[i][j], 0, 0, 0);
    __syncthreads();
  }

  // C/D layout: col = lane&15, row = g*4 + reg.
  const int cr = g * 4, cc = fr;
  float cv[2];
#pragma unroll
  for (int j = 0; j < 2; ++j)
    cv[j] = cvec[(long)b * TD + n0 + 32 * wc + 16 * j + cc];
  const int chunk = nt * 4 + wc;  // 32-col chunk 0..15
  const long rowBase = (long)b * RD + m0 + 64 * wr + cr;
#pragma unroll
  for (int i = 0; i < 4; ++i) {
#pragma unroll
    for (int r = 0; r < 4; ++r) {
      float mx = fmaxf(accS[i][0][r] + cv[0], accS[i][1][r] + cv[1]);
      mx = fmaxf(mx, __shfl_xor(mx, 1));
      mx = fmaxf(mx, __shfl_xor(mx, 2));
      mx = fmaxf(mx, __shfl_xor(mx, 4));
      mx = fmaxf(mx, __shfl_xor(mx, 8));
      float l = 0.f, hs = 0.f;
#pragma unroll
      for (int j = 0; j < 2; ++j) {
        const float e = __expf(accS[i][j][r] + cv[j] - mx);
        l += e;
        hs += e * accH[i][j][r];
      }
      l += __shfl_xor(l, 1); hs += __shfl_xor(hs, 1);
      l += __shfl_xor(l, 2); hs += __shfl_xor(hs, 2);
      l += __shfl_xor(l, 4); hs += __shfl_xor(hs, 4);
      l += __shfl_xor(l, 8); hs += __shfl_xor(hs, 8);
      if (cc == 0) {
        const long idx = (long)chunk * BR + rowBase + 16 * i + r;
        Ms[idx] = mx;
        Ls[idx] = l;
        Hs[idx] = hs;
      }
    }
  }
}

// ---------------- K4: combine 16 chunk-stats per row.
__global__ __launch_bounds__(256) void combine(
    const float* __restrict__ Ms, const float* __restrict__ Ls,
    const float* __restrict__ Hs, const float* __restrict__ rdvec,
    const float* __restrict__ bs, float* __restrict__ out) {
  const int row = blockIdx.x * 256 + threadIdx.x;
  float mv[16];
  float gm = -1e30f;
#pragma unroll
  for (int c = 0; c < 16; ++c) {
    mv[c] = Ms[(long)c * BR + row];
    gm = fmaxf(gm, mv[c]);
  }
  float L = 0.f, HS = 0.f;
#pragma unroll
  for (int c = 0; c < 16; ++c) {
    const float sc = __expf(mv[c] - gm);
    L += Ls[(long)c * BR + row] * sc;
    HS += Hs[(long)c * BR + row] * sc;
  }
  out[row] = HS / L + rdvec[row] + bs[0];
}

extern "C" void kernel_launch(void* const* d_in, const int* in_sizes, int n_in,
                              void* d_out, int out_size, void* d_ws, size_t ws_size,
                              hipStream_t stream) {
  const float* region = (const float*)d_in[0];
  const float* query  = (const float*)d_in[1];
  const float* Wr     = (const float*)d_in[2];
  const float* br     = (const float*)d_in[3];
  const float* Wq     = (const float*)d_in[4];
  // d_in[5] = bq: t-constant per score row, cancels in softmax.
  const float* Ws     = (const float*)d_in[6];
  const float* bs     = (const float*)d_in[7];
  float* out = (float*)d_out;

  // ws layout (~70 MiB; <= proven-safe 74 MiB).
  char* p = (char*)d_ws;
  _Float16* region16 = (_Float16*)p;                   // 32 MiB
  _Float16* query16  = (_Float16*)(p + (32u << 20));   // 16 MiB
  _Float16* Qp       = (_Float16*)(p + (48u << 20));   // 16 MiB
  _Float16* M2       = (_Float16*)(p + (64u << 20));   // 2 MiB
  _Float16* Ws16     = (_Float16*)(p + (66u << 20));   // 4 KiB (Ws1|Ws2)
  float*    wqbr     = (float*)(p + (66u << 20) + 8192);    // 4 KiB
  _Float16* wqbr16   = (_Float16*)(p + (66u << 20) + 12288);// 2 KiB
  float*    cvec     = (float*)(p + (66u << 20) + 16384);   // 32 KiB
  float*    rdvec    = (float*)(p + (66u << 20) + 65536);   // 64 KiB
  float*    Ms       = (float*)(p + (67u << 20));      // 3 x 1 MiB stats
  float*    Ls       = Ms + 16 * BR;
  float*    Hs       = Ls + 16 * BR;

  // K1: M2 GEMM + all conversions + wqbr + rdvec, one launch.
  prep_all<<<dim3(514 + BR + BD * TD), 256, 0, stream>>>(
      Wr, Wq, Ws, br, region, query, M2, Ws16, wqbr, wqbr16,
      region16, rdvec, query16);
  // K2: Qp = NT(query16, M2) + cvec epilogue.
  qp_gemm<<<dim3(512), 512, 0, stream>>>(query16, M2, Qp, wqbr16, cvec);
  // K3: fused S/H + split-softmax stats.
  gemm_fused<<<dim3(512), 512, 0, stream>>>(
      region16, Qp, query16, Ms, Ls, Hs, cvec, Ws16,
      (long)RD * DD, (long)TD * DD);
  // K4: out = HS/L + region.Ws0 + bs.
  combine<<<dim3(BR / 256), 256, 0, stream>>>(Ms, Ls, Hs, rdvec, bs, out);
}